// Round 8
// baseline (742.697 us; speedup 1.0000x reference)
//
#include <hip/hip_runtime.h>
#include <hip/hip_bf16.h>
#include <stdint.h>

// Problem constants (match reference)
#define N_NODES 50000
#define N_EDGES 300000
#define ET      3
#define D_IN    256
#define D_HID   256
#define D_OUT   128
#define KDIM    768          // ET * 256, fused-K for the single GEMM per layer
#define MPAD    50048        // 391 * 128 (GEMM row-tile padded)
#define NTOT    (ET * N_NODES)          // 150000 merged (etype,node) slots
#define ETOT    (ET * N_EDGES)          // 900000 edges total
#define NB1     ((NTOT + 1023) / 1024)  // 147 scan blocks

typedef short bhalf8 __attribute__((ext_vector_type(8)));   // 8 bf16 (4 VGPRs)
typedef float f32x4  __attribute__((ext_vector_type(4)));

// bf16 helpers (RNE), bit-level to avoid header API differences
__device__ __forceinline__ unsigned short f2bf(float f) {
    union { float f; uint32_t u; } c; c.f = f;
    uint32_t u = c.u;
    uint32_t r = (u + 0x7fff + ((u >> 16) & 1)) >> 16;
    return (unsigned short)r;
}
__device__ __forceinline__ float bf2f(unsigned short b) {
    union { uint32_t u; float f; } c; c.u = ((uint32_t)b) << 16;
    return c.f;
}

__device__ __forceinline__ void glds16(const void* g, const void* l) {
    __builtin_amdgcn_global_load_lds(
        (const __attribute__((address_space(1))) unsigned int*)g,
        (__attribute__((address_space(3))) unsigned int*)l, 16, 0, 0);
}

// ---------------------------------------------------------------------------
// CSR build (merged across etypes): histogram -> 3-kernel parallel scan ->
// fill. One global exclusive scan of cnt[150000]; per-etype bases are
// implicit (each etype contributes exactly N_EDGES).
// ---------------------------------------------------------------------------

__global__ void hist_kernel(const int* __restrict__ edges, int* __restrict__ cnt) {
    int i = blockIdx.x * blockDim.x + threadIdx.x;
    if (i >= ETOT) return;
    int e = i / N_EDGES;
    int j = i - e * N_EDGES;
    int dst = edges[(e * 2 + 1) * N_EDGES + j];
    atomicAdd(&cnt[e * N_NODES + dst], 1);
}

// scan1: block b scans its 1024 counts (4/thread), writes block-local
// exclusive positions into rp and the block total into bsum[b].
__global__ __launch_bounds__(256) void scan1_kernel(const int* __restrict__ cnt,
                                                    int* __restrict__ rp,
                                                    int* __restrict__ bsum) {
    int b = blockIdx.x, t = threadIdx.x;
    int idx = b * 1024 + t * 4;
    int4 v = make_int4(0, 0, 0, 0);
    if (idx + 3 < NTOT) v = *(const int4*)&cnt[idx];
    else {
        if (idx + 0 < NTOT) v.x = cnt[idx + 0];
        if (idx + 1 < NTOT) v.y = cnt[idx + 1];
        if (idx + 2 < NTOT) v.z = cnt[idx + 2];
        if (idx + 3 < NTOT) v.w = cnt[idx + 3];
    }
    int s = v.x + v.y + v.z + v.w;
    int lane = t & 63, w = t >> 6;
    int inc = s;
    #pragma unroll
    for (int d = 1; d < 64; d <<= 1) {
        int u = __shfl_up(inc, d, 64);
        if (lane >= d) inc += u;
    }
    __shared__ int ws[4];
    if (lane == 63) ws[w] = inc;
    __syncthreads();
    int wbase = 0;
    for (int i = 0; i < w; ++i) wbase += ws[i];
    int ebase = wbase + inc - s;   // block-local exclusive base for this thread
    if (idx + 0 < NTOT) rp[idx + 0] = ebase;
    if (idx + 1 < NTOT) rp[idx + 1] = ebase + v.x;
    if (idx + 2 < NTOT) rp[idx + 2] = ebase + v.x + v.y;
    if (idx + 3 < NTOT) rp[idx + 3] = ebase + v.x + v.y + v.z;
    if (t == 0) bsum[b] = ws[0] + ws[1] + ws[2] + ws[3];
}

// scan2: one block; exclusive scan of the 147 block sums (Hillis-Steele).
__global__ __launch_bounds__(256) void scan2_kernel(const int* __restrict__ bsum,
                                                    int* __restrict__ bbase) {
    int t = threadIdx.x;
    __shared__ int sh[256];
    int v = (t < NB1) ? bsum[t] : 0;
    sh[t] = v;
    __syncthreads();
    #pragma unroll
    for (int d = 1; d < 256; d <<= 1) {
        int u = (t >= d) ? sh[t - d] : 0;
        __syncthreads();
        sh[t] += u;
        __syncthreads();
    }
    if (t < NB1) bbase[t] = sh[t] - v;   // exclusive
}

// scan3: add block bases; emit final rowptr + cursor copy + sentinel.
__global__ void scan3_kernel(int* __restrict__ rp, int* __restrict__ cursor,
                             const int* __restrict__ bbase) {
    int i = blockIdx.x * blockDim.x + threadIdx.x;
    if (i < NTOT) {
        int v = rp[i] + bbase[i >> 10];
        rp[i] = v;
        cursor[i] = v;
    }
    if (i == 0) rp[NTOT] = ETOT;
}

__global__ void fill_kernel(const int* __restrict__ edges, int* __restrict__ cursor,
                            int* __restrict__ esrc) {
    int i = blockIdx.x * blockDim.x + threadIdx.x;
    if (i >= ETOT) return;
    int e = i / N_EDGES;
    int j = i - e * N_EDGES;
    int src = edges[(e * 2 + 0) * N_EDGES + j];
    int dst = edges[(e * 2 + 1) * N_EDGES + j];
    int p = atomicAdd(&cursor[e * N_NODES + dst], 1);   // global position
    esrc[p] = src;
}

// ---------------------------------------------------------------------------
// Aggregation (pull): one wave per (etype, node). Lane t owns channels
// [4t, 4t+4). 4-wide edge batching for memory-level parallelism; Xh/Xl
// written with NON-TEMPORAL stores (streaming, never re-read here) so the
// gather source (x / h) stays cache-resident. ind[e*N+n] = (cnt>0).
// ---------------------------------------------------------------------------
__global__ void agg_kernel(const float* __restrict__ in, const int* __restrict__ rp,
                           const int* __restrict__ esrc,
                           unsigned short* __restrict__ Xh, unsigned short* __restrict__ Xl,
                           float* __restrict__ ind) {
    int wid = (blockIdx.x * blockDim.x + threadIdx.x) >> 6;
    int lane = threadIdx.x & 63;
    if (wid >= NTOT) return;
    int e = wid / N_NODES;
    int n = wid - e * N_NODES;
    int r0 = rp[wid];
    int r1 = rp[wid + 1];
    int cntv = r1 - r0;
    float4 acc = make_float4(0.f, 0.f, 0.f, 0.f);
    int j = r0;
    // 4-wide batches: 4 independent index loads, then 4 gathers in flight
    for (; j + 4 <= r1; j += 4) {
        int s0 = esrc[j + 0];
        int s1 = esrc[j + 1];
        int s2 = esrc[j + 2];
        int s3 = esrc[j + 3];
        float4 v0 = *((const float4*)(in + (size_t)s0 * 256) + lane);
        float4 v1 = *((const float4*)(in + (size_t)s1 * 256) + lane);
        float4 v2 = *((const float4*)(in + (size_t)s2 * 256) + lane);
        float4 v3 = *((const float4*)(in + (size_t)s3 * 256) + lane);
        acc.x += v0.x + v1.x + v2.x + v3.x;
        acc.y += v0.y + v1.y + v2.y + v3.y;
        acc.z += v0.z + v1.z + v2.z + v3.z;
        acc.w += v0.w + v1.w + v2.w + v3.w;
    }
    for (; j < r1; ++j) {
        int s = esrc[j];
        float4 v = *((const float4*)(in + (size_t)s * 256) + lane);
        acc.x += v.x; acc.y += v.y; acc.z += v.z; acc.w += v.w;
    }
    float sc = (cntv > 0) ? (1.f / (float)cntv) : 0.f;
    acc.x *= sc; acc.y *= sc; acc.z *= sc; acc.w *= sc;
    union { ushort4 u; unsigned long long ll; } ph, pl;
    ph.u.x = f2bf(acc.x); pl.u.x = f2bf(acc.x - bf2f(ph.u.x));
    ph.u.y = f2bf(acc.y); pl.u.y = f2bf(acc.y - bf2f(ph.u.y));
    ph.u.z = f2bf(acc.z); pl.u.z = f2bf(acc.z - bf2f(ph.u.z));
    ph.u.w = f2bf(acc.w); pl.u.w = f2bf(acc.w - bf2f(ph.u.w));
    size_t o = (size_t)n * KDIM + e * 256 + lane * 4;   // 8B-aligned
    __builtin_nontemporal_store(ph.ll, (unsigned long long*)(Xh + o));
    __builtin_nontemporal_store(pl.ll, (unsigned long long*)(Xl + o));
    if (lane == 0) ind[wid] = (cntv > 0) ? 1.f : 0.f;
}

// ---------------------------------------------------------------------------
// W conversion: W[ET, Dout, 256] fp32 -> Wh/Wl[Dout, 768] bf16 (k = e*256+f)
// ---------------------------------------------------------------------------
__global__ void wconv_kernel(const float* __restrict__ W, unsigned short* __restrict__ Wh,
                             unsigned short* __restrict__ Wl, int Dout) {
    int i = blockIdx.x * blockDim.x + threadIdx.x;
    int total = ET * Dout * 256;
    if (i >= total) return;
    int f = i & 255;
    int t = i >> 8;            // e*Dout + co
    int e = t / Dout;
    int co = t - e * Dout;
    float w = W[i];
    unsigned short h = f2bf(w);
    float rem = w - bf2f(h);
    unsigned short l = f2bf(rem);
    int o = co * KDIM + e * 256 + f;
    Wh[o] = h; Wl[o] = l;
}

// ---------------------------------------------------------------------------
// Split-bf16 MFMA GEMM: out[M,Dout] = X[M,768] @ W[Dout,768]^T
//   acc += Ah*Bh + Ah*Bl + Al*Bh   (Al*Bl dropped, ~2^-18 relative)
// 128x128 tile, BK=32, 4 waves (2x2), each wave 64x64 = 4x4 fragments of
// 16x16x32. LDS fragment-linear (conflict-free by construction), DOUBLE-
// BUFFERED: stage K-step t+1 while computing t; one barrier per K-step.
// Epilogue: + sum_e ind[e][row]*bias[e][col], ACT=1 -> leaky_relu(0.01).
// ---------------------------------------------------------------------------
template<int ACT>
__global__ __launch_bounds__(256) void mfma_gemm(
    const unsigned short* __restrict__ Xh, const unsigned short* __restrict__ Xl,
    const unsigned short* __restrict__ Wh, const unsigned short* __restrict__ Wl,
    const float* __restrict__ bias, const float* __restrict__ ind,
    float* __restrict__ out, int M, int Dout) {
    // 2 x 32 KB halves: [Ah | Al | Bh | Bl] x 8 chunks x 512 ushorts
    __shared__ __align__(16) unsigned short smem[2 * 16384];
    const int tid  = threadIdx.x;
    const int lane = tid & 63;
    const int wid  = tid >> 6;           // 0..3
    const int wr   = wid >> 1, wc = wid & 1;
    const int rb   = blockIdx.x * 128;
    const int cb   = blockIdx.y * 128;
    const int lrow = lane & 15;
    const int lcol = (lane >> 4) * 8;    // bf16 element offset within 32-K

    f32x4 acc[4][4];
    #pragma unroll
    for (int i = 0; i < 4; ++i)
        #pragma unroll
        for (int j = 0; j < 4; ++j)
            acc[i][j] = (f32x4){0.f, 0.f, 0.f, 0.f};

    // staging pointers: wave stages subs {2*wid, 2*wid+1} of each array
    const unsigned short* ga_h[2];
    const unsigned short* ga_l[2];
    const unsigned short* gb_h[2];
    const unsigned short* gb_l[2];
    #pragma unroll
    for (int s = 0; s < 2; ++s) {
        int sub  = 2 * wid + s;
        size_t ao = (size_t)(rb + sub * 16 + lrow) * KDIM + lcol;  // rows < MPAD
        size_t bo = (size_t)(cb + sub * 16 + lrow) * KDIM + lcol;
        ga_h[s] = Xh + ao;  ga_l[s] = Xl + ao;
        gb_h[s] = Wh + bo;  gb_l[s] = Wl + bo;
    }

    // prologue: stage K-step 0 into half 0
    #pragma unroll
    for (int s = 0; s < 2; ++s) {
        int sub = 2 * wid + s;
        glds16(ga_h[s], &smem[0 * 4096 + sub * 512]);
        glds16(ga_l[s], &smem[1 * 4096 + sub * 512]);
        glds16(gb_h[s], &smem[2 * 4096 + sub * 512]);
        glds16(gb_l[s], &smem[3 * 4096 + sub * 512]);
    }
    __syncthreads();

    int cur = 0;
    for (int t = 0; t < KDIM / 32; ++t) {
        // stage next K-step into the other half (hidden under MFMA below)
        if (t < KDIM / 32 - 1) {
            unsigned short* sb = &smem[(cur ^ 1) * 16384];
            int nk = (t + 1) * 32;
            #pragma unroll
            for (int s = 0; s < 2; ++s) {
                int sub = 2 * wid + s;
                glds16(ga_h[s] + nk, &sb[0 * 4096 + sub * 512]);
                glds16(ga_l[s] + nk, &sb[1 * 4096 + sub * 512]);
                glds16(gb_h[s] + nk, &sb[2 * 4096 + sub * 512]);
                glds16(gb_l[s] + nk, &sb[3 * 4096 + sub * 512]);
            }
        }
        const unsigned short* sc = &smem[cur * 16384];
        bhalf8 ah[4], al[4], bh[4], bl[4];
        #pragma unroll
        for (int q = 0; q < 4; ++q) {
            ah[q] = *(const bhalf8*)&sc[0 * 4096 + (wr * 4 + q) * 512 + lane * 8];
            al[q] = *(const bhalf8*)&sc[1 * 4096 + (wr * 4 + q) * 512 + lane * 8];
            bh[q] = *(const bhalf8*)&sc[2 * 4096 + (wc * 4 + q) * 512 + lane * 8];
            bl[q] = *(const bhalf8*)&sc[3 * 4096 + (wc * 4 + q) * 512 + lane * 8];
        }
        #pragma unroll
        for (int i = 0; i < 4; ++i)
            #pragma unroll
            for (int j = 0; j < 4; ++j) {
                acc[i][j] = __builtin_amdgcn_mfma_f32_16x16x32_bf16(ah[i], bh[j], acc[i][j], 0, 0, 0);
                acc[i][j] = __builtin_amdgcn_mfma_f32_16x16x32_bf16(ah[i], bl[j], acc[i][j], 0, 0, 0);
                acc[i][j] = __builtin_amdgcn_mfma_f32_16x16x32_bf16(al[i], bh[j], acc[i][j], 0, 0, 0);
            }
        __syncthreads();
        cur ^= 1;
    }

    // epilogue: C/D layout col=lane&15, row=(lane>>4)*4+reg
    const int orow = (lane >> 4) * 4;
    const int ocol = lane & 15;
    #pragma unroll
    for (int i = 0; i < 4; ++i) {
        int rbase = rb + wr * 64 + i * 16 + orow;
        #pragma unroll
        for (int q = 0; q < 4; ++q) {
            int r = rbase + q;
            if (r >= M) continue;
            float i0 = ind[0 * N_NODES + r];
            float i1 = ind[1 * N_NODES + r];
            float i2 = ind[2 * N_NODES + r];
            #pragma unroll
            for (int j = 0; j < 4; ++j) {
                int col = cb + wc * 64 + j * 16 + ocol;
                float t = acc[i][j][q] + i0 * bias[0 * Dout + col]
                                       + i1 * bias[1 * Dout + col]
                                       + i2 * bias[2 * Dout + col];
                if (ACT) t = (t > 0.f) ? t : 0.01f * t;
                out[(size_t)r * Dout + col] = t;
            }
        }
    }
}

// ---------------------------------------------------------------------------
// Launch
// ---------------------------------------------------------------------------
extern "C" void kernel_launch(void* const* d_in, const int* in_sizes, int n_in,
                              void* d_out, int out_size, void* d_ws, size_t ws_size,
                              hipStream_t stream) {
    const float* x      = (const float*)d_in[0];
    const int*   edges1 = (const int*)d_in[1];
    const int*   edges2 = (const int*)d_in[2];
    const float* W1     = (const float*)d_in[3];
    const float* b1     = (const float*)d_in[4];
    const float* W2     = (const float*)d_in[5];
    const float* b2     = (const float*)d_in[6];
    float* out = (float*)d_out;

    // workspace carve-up (~213 MB)
    char* ws = (char*)d_ws;
    size_t p = 0;
    auto alloc = [&](size_t bytes) { size_t o = p; p = (p + bytes + 255) & ~(size_t)255; return o; };
    unsigned short* Xh  = (unsigned short*)(ws + alloc((size_t)MPAD * KDIM * 2));  // 76.9 MB
    unsigned short* Xl  = (unsigned short*)(ws + alloc((size_t)MPAD * KDIM * 2));  // 76.9 MB
    float* h            = (float*)(ws + alloc((size_t)N_NODES * D_HID * 4));       // 51.2 MB
    unsigned short* W1h = (unsigned short*)(ws + alloc((size_t)D_HID * KDIM * 2));
    unsigned short* W1l = (unsigned short*)(ws + alloc((size_t)D_HID * KDIM * 2));
    unsigned short* W2h = (unsigned short*)(ws + alloc((size_t)D_OUT * KDIM * 2));
    unsigned short* W2l = (unsigned short*)(ws + alloc((size_t)D_OUT * KDIM * 2));
    int*   cnt    = (int*)(ws + alloc((size_t)NTOT * 4));
    int*   rp     = (int*)(ws + alloc((size_t)(NTOT + 1) * 4));
    int*   cursor = (int*)(ws + alloc((size_t)NTOT * 4));
    int*   esrc   = (int*)(ws + alloc((size_t)ETOT * 4));
    float* ind    = (float*)(ws + alloc((size_t)NTOT * 4));
    int*   bsum   = (int*)(ws + alloc(256 * 4));
    int*   bbase  = (int*)(ws + alloc(256 * 4));
    (void)ws_size; (void)in_sizes; (void)n_in; (void)out_size;

    const int EB = (ETOT + 255) / 256;
    const int AB = (NTOT * 64 + 255) / 256;
    const int MB = MPAD / 128;   // 391
    const int S3 = (NTOT + 255) / 256;

    // weight split (once per call; graph-capture-safe, pure kernels)
    wconv_kernel<<<(ET * D_HID * 256 + 255) / 256, 256, 0, stream>>>(W1, W1h, W1l, D_HID);
    wconv_kernel<<<(ET * D_OUT * 256 + 255) / 256, 256, 0, stream>>>(W2, W2h, W2l, D_OUT);

    // ---- layer 1 (graph 1) ----
    hipMemsetAsync(cnt, 0, (size_t)NTOT * 4, stream);
    hist_kernel<<<EB, 256, 0, stream>>>(edges1, cnt);
    scan1_kernel<<<NB1, 256, 0, stream>>>(cnt, rp, bsum);
    scan2_kernel<<<1, 256, 0, stream>>>(bsum, bbase);
    scan3_kernel<<<S3, 256, 0, stream>>>(rp, cursor, bbase);
    fill_kernel<<<EB, 256, 0, stream>>>(edges1, cursor, esrc);
    agg_kernel<<<AB, 256, 0, stream>>>(x, rp, esrc, Xh, Xl, ind);
    mfma_gemm<1><<<dim3(MB, D_HID / 128), 256, 0, stream>>>(Xh, Xl, W1h, W1l, b1, ind, h,
                                                            N_NODES, D_HID);
    // ---- layer 2 (graph 2) ----
    hipMemsetAsync(cnt, 0, (size_t)NTOT * 4, stream);
    hist_kernel<<<EB, 256, 0, stream>>>(edges2, cnt);
    scan1_kernel<<<NB1, 256, 0, stream>>>(cnt, rp, bsum);
    scan2_kernel<<<1, 256, 0, stream>>>(bsum, bbase);
    scan3_kernel<<<S3, 256, 0, stream>>>(rp, cursor, bbase);
    fill_kernel<<<EB, 256, 0, stream>>>(edges2, cursor, esrc);
    agg_kernel<<<AB, 256, 0, stream>>>(h, rp, esrc, Xh, Xl, ind);
    mfma_gemm<0><<<dim3(MB, D_OUT / 128), 256, 0, stream>>>(Xh, Xl, W2h, W2l, b2, ind, out,
                                                            N_NODES, D_OUT);
}